// Round 7
// baseline (464.230 us; speedup 1.0000x reference)
//
#include <hip/hip_runtime.h>

// Heat equation, 2 materials, N=512, 499 steps, all frames written.
// Temporal tiling: K=16 steps/launch, 32 dispatches, 1024-thread blocks.
// R7: wave = 4-row x 64-col slab (lane = column) with GHOST DEPTH 4:
// each wave keeps rows -4..7 in registers and recomputes the shrinking
// halo locally for 4 sub-steps (10,8,6,4 rows), so the cross-wave LDS
// exchange + barrier runs only 3x per launch (vs 15x). Left/right via
// DPP lane shifts. LDS-only barrier (no vmcnt drain) keeps frame stores
// async. Junk propagation is 1 row/col per step as before; owned 32x32
// stays exact through 16 steps.

#define GN 512
#define NSTEPS 499
#define MBND 256
#define INV_DX2 261121.0f     // 511^2 = 1/dx^2
#define DT 5e-7f

#define TO 32                 // owned tile edge
#define KMAX 16               // steps per launch (= trapezoid margin)
#define GSLOT (4 * 64)        // floats per wave-group slot in LDS
#define PSTRIDE (18 * GSLOT)  // per-parity buffer (16 groups + 2 guards)

__device__ __forceinline__ void lds_barrier() {
    // LDS-visibility-only workgroup barrier: do NOT drain vmcnt (global
    // frame stores stay in flight across steps).
    asm volatile("s_waitcnt lgkmcnt(0)" ::: "memory");
    __builtin_amdgcn_s_barrier();
    asm volatile("" ::: "memory");
}

// lane i <- lane i-1 (wave_shr:1); lane 0 keeps own value (junk-safe:
// region edge, outside validity trapezoid).
__device__ __forceinline__ float dpp_shr1(float x) {
    int v = __builtin_amdgcn_update_dpp(__float_as_int(x), __float_as_int(x),
                                        0x138, 0xf, 0xf, false);
    return __int_as_float(v);
}
// lane i <- lane i+1 (wave_shl:1)
__device__ __forceinline__ float dpp_shl1(float x) {
    int v = __builtin_amdgcn_update_dpp(__float_as_int(x), __float_as_int(x),
                                        0x130, 0xf, 0xf, false);
    return __int_as_float(v);
}

// One group of D sub-steps entirely in registers. X[r+4] = row r (-4..7).
// Sub-step q computes rows [-(D-1-q), 3+(D-1-q)] (needs one extra row each
// side as input). Rows 0..3 always computed -> stored every sub-step.
template<int D>
__device__ __forceinline__ void run_group(
    float (&X)[12], const bool (&brx)[12],
    float Ac, bool ifcc, bool bcc, float k1, float k2, float invk,
    bool anyIfc, bool anyBC, bool anyBR,
    bool own, float*& d0, float*& d2)
{
    #pragma unroll
    for (int q = 0; q < D; ++q) {
        const int lo = -(D - 1 - q);
        const int hi = 3 + (D - 1 - q);
        float Nv[12];
        #pragma unroll
        for (int r = lo; r <= hi; ++r) {
            const float c  = X[r + 4];
            const float lf = dpp_shr1(c), rt = dpp_shl1(c);
            const float s4 = (X[r + 3] + X[r + 5]) + (lf + rt);
            float v = fmaf(Ac, fmaf(-4.0f, c, s4), c);
            if (anyIfc) v = ifcc ? (k1 * rt + k2 * lf) * invk : v; // OLD nbrs
            if (anyBC)  v = bcc ? 0.0f : v;
            if (anyBR)  v = brx[r + 4] ? 0.0f : v;
            Nv[r + 4] = v;
        }
        #pragma unroll
        for (int r = lo; r <= hi; ++r) X[r + 4] = Nv[r + 4];

        // stream owned rows 0..3 (async; barrier never drains vmcnt)
        if (own) { d0[0] = X[4]; d0[GN] = X[5]; d2[0] = X[6]; d2[GN] = X[7]; }
        d0 += (long)GN * GN; d2 += (long)GN * GN;
    }
}

template<int STEPS>   // 16 (full) or 3 (tail)
__global__ __launch_bounds__(1024) void heat_multi(
    const float* __restrict__ Tin, float* __restrict__ outBase,
    const float* __restrict__ k1p, const float* __restrict__ k2p,
    const float* __restrict__ a1p, const float* __restrict__ a2p)
{
    __shared__ float S[2 * PSTRIDE];

    const int t    = threadIdx.x;            // 0..1023
    const int lane = t & 63;                 // column within 64-wide region
    const int ty   = t >> 6;                 // wave id = row group, 0..15
    const int bi = blockIdx.x >> 4;          // 16x16 tile grid
    const int bj = blockIdx.x & 15;
    const int gi0 = bi * TO - KMAX;
    const int gj0 = bj * TO - KMAX;
    const int gj  = gj0 + lane;              // this thread's global column
    const int gr0 = gi0 + ty * 4;            // first own global row

    const float k1 = k1p[0], k2 = k2p[0];
    const float a1 = a1p[0], a2 = a2p[0];
    const float invk = 1.0f / (k1 + k2);
    const float Ac = (DT * INV_DX2) * ((gj < MBND) ? a1 : a2);
    const bool ifcc = (gj == MBND - 1);
    const bool bcc  = (gj <= 0) || (gj >= GN - 1);

    bool brx[12];
    #pragma unroll
    for (int r = -4; r <= 7; ++r) {
        const int gi = gr0 + r;
        brx[r + 4] = (gi <= 0) || (gi >= GN - 1);
    }

    // block-uniform specialization (scalar branches)
    const bool anyIfc = (bj == 7) || (bj == 8);
    const bool anyBC  = (bj == 0) || (bj == 15);
    const bool anyBR  = (bi == 0) || (bi == 15);

    // ---- initial state: rows -4..7 straight from global (coalesced)
    const bool vc = ((unsigned)gj < GN);
    float X[12];
    #pragma unroll
    for (int r = -4; r <= 7; ++r) {
        const int gi = gr0 + r;
        X[r + 4] = (vc && (unsigned)gi < GN) ? Tin[(long)gi * GN + gj] : 0.0f;
    }

    const bool own = (ty >= 4) && (ty < 12) && (lane >= 16) && (lane < 48);
    float* d0 = outBase + ((long)gr0 * GN + gj);
    float* d2 = d0 + 2L * GN;

    if constexpr (STEPS == 16) {
        run_group<4>(X, brx, Ac, ifcc, bcc, k1, k2, invk,
                     anyIfc, anyBC, anyBR, own, d0, d2);
        #pragma unroll
        for (int g = 0; g < 3; ++g) {
            // exchange: publish own rows (time t) -> barrier -> read ghosts
            const int p = (g & 1) * PSTRIDE;
            float* wp = &S[p + (ty + 1) * GSLOT + lane];
            wp[0] = X[4]; wp[64] = X[5]; wp[128] = X[6]; wp[192] = X[7];
            lds_barrier();
            const float* rT = &S[p + ty * GSLOT + lane];        // group ty-1
            const float* rB = &S[p + (ty + 2) * GSLOT + lane];  // group ty+1
            X[0] = rT[0];  X[1] = rT[64];  X[2]  = rT[128]; X[3]  = rT[192];
            X[8] = rB[0];  X[9] = rB[64];  X[10] = rB[128]; X[11] = rB[192];

            run_group<4>(X, brx, Ac, ifcc, bcc, k1, k2, invk,
                         anyIfc, anyBC, anyBR, own, d0, d2);
        }
    } else {
        // 3-step tail: one group, ghost depth 3, no LDS, no barriers
        run_group<3>(X, brx, Ac, ifcc, bcc, k1, k2, invk,
                     anyIfc, anyBC, anyBR, own, d0, d2);
    }
}

extern "C" void kernel_launch(void* const* d_in, const int* in_sizes, int n_in,
                              void* d_out, int out_size, void* d_ws, size_t ws_size,
                              hipStream_t stream)
{
    const float* u0 = (const float*)d_in[0];
    const float* k1 = (const float*)d_in[1];
    const float* k2 = (const float*)d_in[2];
    const float* a1 = (const float*)d_in[3];
    const float* a2 = (const float*)d_in[4];
    float* out = (float*)d_out;

    const int pts = GN * GN;
    const float* src = u0;
    int done = 0;
    while (done < NSTEPS) {
        int steps = NSTEPS - done;
        if (steps > KMAX) steps = KMAX;
        float* ob = out + (size_t)done * pts;
        if (steps == KMAX)
            heat_multi<KMAX><<<256, 1024, 0, stream>>>(src, ob, k1, k2, a1, a2);
        else  // NSTEPS = 31*16 + 3 -> remainder is always 3
            heat_multi<3><<<256, 1024, 0, stream>>>(src, ob, k1, k2, a1, a2);
        src = ob + (size_t)(steps - 1) * pts;
        done += steps;
    }
}

// Round 8
// 387.272 us; speedup vs baseline: 1.1987x; 1.1987x over previous
//
#include <hip/hip_runtime.h>

// Heat equation, 2 materials, N=512, 499 steps, all frames written.
// Temporal tiling: K=16 steps/launch, 32 dispatches, 1024-thread blocks,
// thread = 1x4 strip (row ty, cols lj0..lj0+3) of a 64x64 halo'd region.
// R8: DEPTH-2 exchange — per 2 steps: 4x ds_read_b128 (rows ty+-1, ty+-2),
// locally compute rows ty-1,ty,ty+1 @t+1 then row ty @t+2 in registers,
// 1x ds_write_b128 + 1 barrier. Left/right via DPP row_shr/shl (VALU pipe,
// 16-lane rows == ty groups). 1 float4 global store per step (vmcnt<=16).
// LDS-only barrier (no vmcnt drain) keeps frame stores async.

#define GN 512
#define NSTEPS 499
#define MBND 256
#define INV_DX2 261121.0f     // 511^2 = 1/dx^2
#define DT 5e-7f

#define TO 32                 // owned tile edge
#define KMAX 16               // steps per launch (= trapezoid margin)
#define LOAD 64               // TO + 2*KMAX
#define LSTR 68               // padded LDS row stride (floats)

__device__ __forceinline__ void lds_barrier() {
    // LDS-visibility-only workgroup barrier: do NOT drain vmcnt (global
    // frame stores stay in flight across steps).
    asm volatile("s_waitcnt lgkmcnt(0)" ::: "memory");
    __builtin_amdgcn_s_barrier();
    asm volatile("" ::: "memory");
}

// DPP shifts within 16-lane rows (= one ty group). Out-of-range lanes keep
// their own value (bound_ctrl=0, old=src) -> junk only at region edges,
// outside the validity trapezoid.
__device__ __forceinline__ float dpp_row_shr1(float x) {  // lane i <- i-1
    int v = __builtin_amdgcn_update_dpp(__float_as_int(x), __float_as_int(x),
                                        0x111, 0xf, 0xf, false);
    return __int_as_float(v);
}
__device__ __forceinline__ float dpp_row_shl1(float x) {  // lane i <- i+1
    int v = __builtin_amdgcn_update_dpp(__float_as_int(x), __float_as_int(x),
                                        0x101, 0xf, 0xf, false);
    return __int_as_float(v);
}

struct Prm {
    float Ac[4]; bool ifc[4]; bool bcl[4];
    float k1, k2, invk;
    bool aI, aC, aR;
};

// One stencil row update: x = row values, up/dn = vertical neighbors.
__device__ __forceinline__ void srow(const float x[4], const float up[4],
                                     const float dn[4], float out[4],
                                     const Prm& p, bool brF)
{
    const float lf = dpp_row_shr1(x[3]);
    const float rg = dpp_row_shl1(x[0]);
    const float le[4] = {lf, x[0], x[1], x[2]};
    const float ri[4] = {x[1], x[2], x[3], rg};
    #pragma unroll
    for (int j = 0; j < 4; ++j) {
        float v = fmaf(p.Ac[j], fmaf(-4.0f, x[j], (up[j] + dn[j]) + (le[j] + ri[j])), x[j]);
        if (p.aI) v = p.ifc[j] ? (p.k1 * ri[j] + p.k2 * le[j]) * p.invk : v;
        if (p.aC) v = p.bcl[j] ? 0.0f : v;
        if (p.aR) v = brF ? 0.0f : v;
        out[j] = v;
    }
}

__device__ __forceinline__ void ld4(float d[4], const float* s) {
    const float4 v = *(const float4*)s;
    d[0] = v.x; d[1] = v.y; d[2] = v.z; d[3] = v.w;
}

template<int STEPS>   // 16 (full) or 3 (tail)
__global__ __launch_bounds__(1024) void heat_multi(
    const float* __restrict__ Tin, float* __restrict__ outBase,
    const float* __restrict__ k1p, const float* __restrict__ k2p,
    const float* __restrict__ a1p, const float* __restrict__ a2p)
{
    __shared__ float Sb[2][LOAD][LSTR];

    const int t  = threadIdx.x;              // 0..1023
    const int bi = blockIdx.x >> 4;          // 16x16 tile grid
    const int bj = blockIdx.x & 15;
    const int gi0 = bi * TO - KMAX;
    const int gj0 = bj * TO - KMAX;

    const int tx = t & 15, ty = t >> 4;      // 64 rows x 16 col-groups
    const int lj0 = tx * 4;

    // ---- stage region @t0 into Sb[0]; own float4 == (ty,lj0) assignment
    float C[4];
    {
        const bool innerB = (gi0 >= 0) && (gi0 + LOAD <= GN) &&
                            (gj0 >= 0) && (gj0 + LOAD <= GN);
        float4 v;
        if (innerB) {
            v = *(const float4*)&Tin[(size_t)(gi0 + ty) * GN + (gj0 + lj0)];
        } else {
            const int gi_ = gi0 + ty;
            float tmp[4];
            #pragma unroll
            for (int e = 0; e < 4; ++e) {
                const int gj_ = gj0 + lj0 + e;
                tmp[e] = ((unsigned)gi_ < GN && (unsigned)gj_ < GN)
                         ? Tin[(size_t)gi_ * GN + gj_] : 0.0f;
            }
            v = make_float4(tmp[0], tmp[1], tmp[2], tmp[3]);
        }
        *(float4*)&Sb[0][ty][lj0] = v;
        C[0] = v.x; C[1] = v.y; C[2] = v.z; C[3] = v.w;
    }

    // clamped neighbor-row indices (junk-safe: outside trapezoid)
    const int rm1 = (ty >= 1) ? ty - 1 : 0;
    const int rm2 = (ty >= 2) ? ty - 2 : 0;
    const int rp1 = (ty <= LOAD - 2) ? ty + 1 : LOAD - 1;
    const int rp2 = (ty <= LOAD - 3) ? ty + 2 : LOAD - 1;

    Prm p;
    p.k1 = k1p[0]; p.k2 = k2p[0];
    const float a1 = a1p[0], a2 = a2p[0];
    p.invk = 1.0f / (p.k1 + p.k2);
    #pragma unroll
    for (int j = 0; j < 4; ++j) {
        const int gj_ = gj0 + lj0 + j;
        p.Ac[j]  = (DT * INV_DX2) * ((gj_ < MBND) ? a1 : a2);
        p.ifc[j] = (gj_ == MBND - 1);
        p.bcl[j] = (gj_ <= 0) || (gj_ >= GN - 1);
    }
    p.aI = (bj == 7) || (bj == 8);
    p.aC = (bj == 0) || (bj == 15);
    p.aR = (bi == 0) || (bi == 15);

    const int gi = gi0 + ty;
    const bool brM = (gi - 1 <= 0) || (gi - 1 >= GN - 1);
    const bool br0 = (gi     <= 0) || (gi     >= GN - 1);
    const bool brP = (gi + 1 <= 0) || (gi + 1 >= GN - 1);

    const bool own = (tx >= 4) && (tx < 12) && (ty >= KMAX) && (ty < KMAX + TO);
    float* dst = outBase + ((long)gi * GN + (gj0 + lj0));

    lds_barrier();

    constexpr int NG = STEPS / 2;            // 8 for 16-step, 1 for 3-step
    #pragma unroll
    for (int g = 0; g < NG; ++g) {
        const float (*Rb)[LSTR] = Sb[g & 1];
        float (*Wb)[LSTR] = Sb[(g + 1) & 1];

        float A[4], B[4], D[4], E[4];
        ld4(A, &Rb[rm2][lj0]);
        ld4(B, &Rb[rm1][lj0]);
        ld4(D, &Rb[rp1][lj0]);
        ld4(E, &Rb[rp2][lj0]);

        // step A (t -> t+1): rows ty-1, ty, ty+1 locally
        float nB[4], nC[4], nD[4];
        srow(B, A, C, nB, p, brM);
        srow(C, B, D, nC, p, br0);
        srow(D, C, E, nD, p, brP);
        if (own) *(float4*)dst = make_float4(nC[0], nC[1], nC[2], nC[3]);
        dst += (long)GN * GN;

        // step B (t+1 -> t+2): row ty from local neighbors, no LDS
        float n2[4];
        srow(nC, nB, nD, n2, p, br0);
        if (own) *(float4*)dst = make_float4(n2[0], n2[1], n2[2], n2[3]);
        dst += (long)GN * GN;

        C[0] = n2[0]; C[1] = n2[1]; C[2] = n2[2]; C[3] = n2[3];

        if (g < NG - 1 || STEPS == 3) {      // publish row ty @t+2
            *(float4*)&Wb[ty][lj0] = make_float4(C[0], C[1], C[2], C[3]);
            lds_barrier();
        }
    }

    if constexpr (STEPS == 3) {
        // final odd step: neighbor rows @t+2 are in Sb[1]
        float B[4], D[4];
        ld4(B, &Sb[1][rm1][lj0]);
        ld4(D, &Sb[1][rp1][lj0]);
        float nC[4];
        srow(C, B, D, nC, p, br0);
        if (own) *(float4*)dst = make_float4(nC[0], nC[1], nC[2], nC[3]);
    }
}

extern "C" void kernel_launch(void* const* d_in, const int* in_sizes, int n_in,
                              void* d_out, int out_size, void* d_ws, size_t ws_size,
                              hipStream_t stream)
{
    const float* u0 = (const float*)d_in[0];
    const float* k1 = (const float*)d_in[1];
    const float* k2 = (const float*)d_in[2];
    const float* a1 = (const float*)d_in[3];
    const float* a2 = (const float*)d_in[4];
    float* out = (float*)d_out;

    const int pts = GN * GN;
    const float* src = u0;
    int done = 0;
    while (done < NSTEPS) {
        int steps = NSTEPS - done;
        if (steps > KMAX) steps = KMAX;
        float* ob = out + (size_t)done * pts;
        if (steps == KMAX)
            heat_multi<KMAX><<<256, 1024, 0, stream>>>(src, ob, k1, k2, a1, a2);
        else  // NSTEPS = 31*16 + 3 -> remainder is always 3
            heat_multi<3><<<256, 1024, 0, stream>>>(src, ob, k1, k2, a1, a2);
        src = ob + (size_t)(steps - 1) * pts;
        done += steps;
    }
}

// Round 9
// 319.631 us; speedup vs baseline: 1.4524x; 1.2116x over previous
//
#include <hip/hip_runtime.h>

// Heat equation, 2 materials, N=512, 499 steps, all frames written.
// Temporal tiling: K=16 steps/launch, 32 dispatches, 1024-thread blocks,
// thread = 1x4 strip (row ty, cols lj0..lj0+3) of a 64x64 halo'd region.
// R9: NO per-step block barrier. Cross-wave sync is nearest-neighbor LDS
// flags: wave w waits flag[w+-1] >= s-1, reads rows ty+-1 from parity
// buffer (s-1)&1, computes (left/right via DPP, VALU pipe), writes its row
// to buffer s&1, then flag[w]=s (release). Neighbor skew <= 1 step makes
// 2 parity buffers sufficient; waves pipeline instead of convoying.
// Global frame stores stay fully async (no vmcnt wait in the loop).

#define GN 512
#define NSTEPS 499
#define MBND 256
#define INV_DX2 261121.0f     // 511^2 = 1/dx^2
#define DT 5e-7f

#define TO 32                 // owned tile edge
#define KMAX 16               // steps per launch (= trapezoid margin)
#define LOAD 64               // TO + 2*KMAX
#define LSTR 68               // padded LDS row stride (floats)

// DPP shifts within 16-lane rows (= one ty row of threads). Out-of-range
// lanes keep their own value (bound_ctrl=0, old=src) -> junk only at
// region edges, outside the validity trapezoid.
__device__ __forceinline__ float dpp_row_shr1(float x) {  // lane i <- i-1
    int v = __builtin_amdgcn_update_dpp(__float_as_int(x), __float_as_int(x),
                                        0x111, 0xf, 0xf, false);
    return __int_as_float(v);
}
__device__ __forceinline__ float dpp_row_shl1(float x) {  // lane i <- i+1
    int v = __builtin_amdgcn_update_dpp(__float_as_int(x), __float_as_int(x),
                                        0x101, 0xf, 0xf, false);
    return __int_as_float(v);
}

__device__ __forceinline__ void wait_ge(const int* f, int v) {
    while (__atomic_load_n(f, __ATOMIC_ACQUIRE) < v) {
        __builtin_amdgcn_s_sleep(1);
    }
}

struct Prm {
    float Ac[4]; bool ifc[4]; bool bcl[4];
    float k1, k2, invk;
    bool aI, aC, aR;
};

// One stencil row update: x = row values, up/dn = vertical neighbors.
__device__ __forceinline__ void srow(const float x[4], const float up[4],
                                     const float dn[4], float out[4],
                                     const Prm& p, bool brF)
{
    const float lf = dpp_row_shr1(x[3]);
    const float rg = dpp_row_shl1(x[0]);
    const float le[4] = {lf, x[0], x[1], x[2]};
    const float ri[4] = {x[1], x[2], x[3], rg};
    #pragma unroll
    for (int j = 0; j < 4; ++j) {
        float v = fmaf(p.Ac[j], fmaf(-4.0f, x[j], (up[j] + dn[j]) + (le[j] + ri[j])), x[j]);
        if (p.aI) v = p.ifc[j] ? (p.k1 * ri[j] + p.k2 * le[j]) * p.invk : v; // OLD nbrs
        if (p.aC) v = p.bcl[j] ? 0.0f : v;
        if (p.aR) v = brF ? 0.0f : v;
        out[j] = v;
    }
}

__device__ __forceinline__ void ld4(float d[4], const float* s) {
    const float4 v = *(const float4*)s;
    d[0] = v.x; d[1] = v.y; d[2] = v.z; d[3] = v.w;
}

template<int STEPS>   // 16 (full) or 3 (tail)
__global__ __launch_bounds__(1024) void heat_multi(
    const float* __restrict__ Tin, float* __restrict__ outBase,
    const float* __restrict__ k1p, const float* __restrict__ k2p,
    const float* __restrict__ a1p, const float* __restrict__ a2p)
{
    __shared__ float Sb[2][LOAD][LSTR];
    __shared__ int flagArr[16];

    const int t  = threadIdx.x;              // 0..1023
    const int bi = blockIdx.x >> 4;          // 16x16 tile grid
    const int bj = blockIdx.x & 15;
    const int gi0 = bi * TO - KMAX;
    const int gj0 = bj * TO - KMAX;

    const int tx = t & 15, ty = t >> 4;      // 64 rows x 16 col-groups
    const int w  = t >> 6;                   // wave id 0..15 (4 rows each)
    const int lj0 = tx * 4;

    // ---- stage region @t0 into Sb[0]; own float4 == (ty,lj0) assignment
    float C[4];
    {
        const bool innerB = (gi0 >= 0) && (gi0 + LOAD <= GN) &&
                            (gj0 >= 0) && (gj0 + LOAD <= GN);
        float4 v;
        if (innerB) {
            v = *(const float4*)&Tin[(size_t)(gi0 + ty) * GN + (gj0 + lj0)];
        } else {
            const int gi_ = gi0 + ty;
            float tmp[4];
            #pragma unroll
            for (int e = 0; e < 4; ++e) {
                const int gj_ = gj0 + lj0 + e;
                tmp[e] = ((unsigned)gi_ < GN && (unsigned)gj_ < GN)
                         ? Tin[(size_t)gi_ * GN + gj_] : 0.0f;
            }
            v = make_float4(tmp[0], tmp[1], tmp[2], tmp[3]);
        }
        *(float4*)&Sb[0][ty][lj0] = v;
        C[0] = v.x; C[1] = v.y; C[2] = v.z; C[3] = v.w;
    }
    if (t < 16) flagArr[t] = 0;              // "state 0 published"
    __syncthreads();                         // the ONLY block-wide barrier

    // clamped neighbor-row indices (junk-safe: outside trapezoid)
    const int rm1 = (ty >= 1) ? ty - 1 : 0;
    const int rp1 = (ty <= LOAD - 2) ? ty + 1 : LOAD - 1;
    const int wm1 = (w == 0) ? 0 : w - 1;
    const int wp1 = (w == 15) ? 15 : w + 1;

    Prm p;
    p.k1 = k1p[0]; p.k2 = k2p[0];
    const float a1 = a1p[0], a2 = a2p[0];
    p.invk = 1.0f / (p.k1 + p.k2);
    #pragma unroll
    for (int j = 0; j < 4; ++j) {
        const int gj_ = gj0 + lj0 + j;
        p.Ac[j]  = (DT * INV_DX2) * ((gj_ < MBND) ? a1 : a2);
        p.ifc[j] = (gj_ == MBND - 1);
        p.bcl[j] = (gj_ <= 0) || (gj_ >= GN - 1);
    }
    p.aI = (bj == 7) || (bj == 8);
    p.aC = (bj == 0) || (bj == 15);
    p.aR = (bi == 0) || (bi == 15);

    const int gi = gi0 + ty;
    const bool br0 = (gi <= 0) || (gi >= GN - 1);

    const bool own = (tx >= 4) && (tx < 12) && (ty >= KMAX) && (ty < KMAX + TO);
    float* dst = outBase + ((long)gi * GN + (gj0 + lj0));

    #pragma unroll
    for (int s = 1; s <= STEPS; ++s) {
        // 1) wait until neighbor waves have published state s-1
        //    (s==1: flags start at 0 -> condition already true, skip)
        if (s > 1) {
            wait_ge(&flagArr[wm1], s - 1);
            wait_ge(&flagArr[wp1], s - 1);
        }
        // 2) read vertical neighbors (state s-1)
        const float (*Rb)[LSTR] = Sb[(s - 1) & 1];
        float B[4], D[4];
        ld4(B, &Rb[rm1][lj0]);
        ld4(D, &Rb[rp1][lj0]);

        // 3) compute state s for own row
        float nC[4];
        srow(C, B, D, nC, p, br0);

        // 4) publish row + 5) raise flag (release orders data before flag)
        if (s < STEPS) {
            float (*Wb)[LSTR] = Sb[s & 1];
            *(float4*)&Wb[ty][lj0] = make_float4(nC[0], nC[1], nC[2], nC[3]);
            if ((t & 63) == 0)
                __atomic_store_n(&flagArr[w], s, __ATOMIC_RELEASE);
        }
        C[0] = nC[0]; C[1] = nC[1]; C[2] = nC[2]; C[3] = nC[3];

        // 6) stream owned strip (async; nothing in the loop drains vmcnt)
        if (own) *(float4*)dst = make_float4(C[0], C[1], C[2], C[3]);
        dst += (long)GN * GN;
    }
}

extern "C" void kernel_launch(void* const* d_in, const int* in_sizes, int n_in,
                              void* d_out, int out_size, void* d_ws, size_t ws_size,
                              hipStream_t stream)
{
    const float* u0 = (const float*)d_in[0];
    const float* k1 = (const float*)d_in[1];
    const float* k2 = (const float*)d_in[2];
    const float* a1 = (const float*)d_in[3];
    const float* a2 = (const float*)d_in[4];
    float* out = (float*)d_out;

    const int pts = GN * GN;
    const float* src = u0;
    int done = 0;
    while (done < NSTEPS) {
        int steps = NSTEPS - done;
        if (steps > KMAX) steps = KMAX;
        float* ob = out + (size_t)done * pts;
        if (steps == KMAX)
            heat_multi<KMAX><<<256, 1024, 0, stream>>>(src, ob, k1, k2, a1, a2);
        else  // NSTEPS = 31*16 + 3 -> remainder is always 3
            heat_multi<3><<<256, 1024, 0, stream>>>(src, ob, k1, k2, a1, a2);
        src = ob + (size_t)(steps - 1) * pts;
        done += steps;
    }
}